// Round 1
// 412.135 us; speedup vs baseline: 1.0404x; 1.0404x over previous
//
#include <hip/hip_runtime.h>

#define B_ 32
#define D_ 128
#define LC 2048
#define LQ 512
#define CCH 16   // c-chunks for colstats partials

#define NEGINF (-3.0e38f)

typedef __attribute__((ext_vector_type(8))) short bf16x8;
typedef __attribute__((ext_vector_type(4))) float f32x4;
typedef __attribute__((ext_vector_type(8))) unsigned short us8;
typedef __attribute__((ext_vector_type(8))) _Float16 f16x8;

__device__ __forceinline__ unsigned short bf16rne(float x) {
    unsigned int u = __float_as_uint(x);
    u = (u + 0x7FFFu + ((u >> 16) & 1u)) >> 16;
    return (unsigned short)u;
}

__device__ __forceinline__ void gll16(const void* g, void* l) {
    __builtin_amdgcn_global_load_lds((const __attribute__((address_space(1))) void*)g,
                                     (__attribute__((address_space(3))) void*)l, 16, 0, 0);
}

// ---------- K0: outv[b,x] = sum_d X[b,d,x] * w[d] ----------
__global__ void k_dotw(const float* __restrict__ X, const float* __restrict__ w,
                       float* __restrict__ outv, int L) {
    int idx = blockIdx.x * 256 + threadIdx.x;
    int b = idx / L, x = idx - b * L;
    const float* Xp = X + (size_t)b * D_ * L + x;
    float acc = 0.f;
#pragma unroll 8
    for (int dd = 0; dd < D_; ++dd) acc += Xp[(size_t)dd * L] * w[dd];
    outv[idx] = acc;
}

// ---------- prep C: Ctw[c][d] = bf16(C[d][c]*wmul[d]) (transposed), Cb16[d][c] = bf16(C[d][c]) ----------
__global__ void k_prep_C(const float* __restrict__ C, const float* __restrict__ wmul,
                         short* __restrict__ Ctw, short* __restrict__ Cb16) {
    int b = blockIdx.y, c0 = blockIdx.x * 64;
    __shared__ float Tf[128][65];
    __shared__ float wm[128];
    int t = threadIdx.x;
    if (t < 128) wm[t] = wmul[t];
    const float* Cb = C + (size_t)b * D_ * LC;
#pragma unroll
    for (int i = 0; i < 8; ++i) {
        int idx = t + i * 256;
        int d = idx >> 4, c4 = idx & 15;
        float4 v = *(const float4*)(Cb + (size_t)d * LC + c0 + c4 * 4);
        Tf[d][c4 * 4 + 0] = v.x; Tf[d][c4 * 4 + 1] = v.y;
        Tf[d][c4 * 4 + 2] = v.z; Tf[d][c4 * 4 + 3] = v.w;
        ushort4 cv;
        cv.x = bf16rne(v.x); cv.y = bf16rne(v.y); cv.z = bf16rne(v.z); cv.w = bf16rne(v.w);
        *(ushort4*)(Cb16 + ((size_t)b * D_ + d) * LC + c0 + c4 * 4) = cv;
    }
    __syncthreads();
    int c_l = t & 63, g = t >> 6;
    unsigned short u[32];
#pragma unroll
    for (int j = 0; j < 32; ++j) {
        int d = g * 32 + j;
        u[j] = bf16rne(Tf[d][c_l] * wm[d]);
    }
    short* dst = Ctw + ((size_t)b * LC + c0 + c_l) * D_ + g * 32;
#pragma unroll
    for (int k = 0; k < 4; ++k) *(us8*)(dst + k * 8) = *(const us8*)&u[k * 8];
}

// ---------- prep Q: Qt16[q][d] = bf16(Q[d][q]) (transposed), W[n=d][q] = bf16(Q[d][q]) ----------
__global__ void k_prep_Q(const float* __restrict__ Q, short* __restrict__ Qt16,
                         short* __restrict__ Wf) {
    int b = blockIdx.y, q0 = blockIdx.x * 64;
    __shared__ float Tf[128][65];
    int t = threadIdx.x;
    const float* Qb = Q + (size_t)b * D_ * LQ;
#pragma unroll
    for (int i = 0; i < 8; ++i) {
        int idx = t + i * 256;
        int d = idx >> 4, q4 = idx & 15;
        float4 v = *(const float4*)(Qb + (size_t)d * LQ + q0 + q4 * 4);
        Tf[d][q4 * 4 + 0] = v.x; Tf[d][q4 * 4 + 1] = v.y;
        Tf[d][q4 * 4 + 2] = v.z; Tf[d][q4 * 4 + 3] = v.w;
        ushort4 cv;
        cv.x = bf16rne(v.x); cv.y = bf16rne(v.y); cv.z = bf16rne(v.z); cv.w = bf16rne(v.w);
        *(ushort4*)(Wf + ((size_t)b * 256 + d) * LQ + q0 + q4 * 4) = cv;
    }
    __syncthreads();
    int q_l = t & 63, g = t >> 6;
    unsigned short u[32];
#pragma unroll
    for (int j = 0; j < 32; ++j) u[j] = bf16rne(Tf[g * 32 + j][q_l]);
    short* dst = Qt16 + ((size_t)b * LQ + q0 + q_l) * D_ + g * 32;
#pragma unroll
    for (int k = 0; k < 4; ++k) *(us8*)(dst + k * 8) = *(const us8*)&u[k * 8];
}

// ---------- K1: S[c][q] via MFMA, stored fp16 ----------
__global__ __launch_bounds__(256) void k_S_mfma(const short* __restrict__ Ctw,
                                                const short* __restrict__ Qt16,
                                                const float* __restrict__ s0,
                                                const float* __restrict__ s1,
                                                const float* __restrict__ bias,
                                                _Float16* __restrict__ S16) {
    int b = blockIdx.y;
    int cT = blockIdx.x >> 2, qT = blockIdx.x & 3;
    int c0 = cT * 128, q0 = qT * 128;
    int t = threadIdx.x, w = t >> 6, l = t & 63;
    int wm_ = w >> 1, wn = w & 1;
    __shared__ short As[128 * 64];
    __shared__ short Bs[128 * 64];
    f32x4 acc[4][4] = {};
    const short* Arow = Ctw + ((size_t)b * LC + c0) * D_;
    const short* Brow = Qt16 + ((size_t)b * LQ + q0) * D_;
    int lr = l >> 3, sl = l & 7;
    for (int kt = 0; kt < 2; ++kt) {
        __syncthreads();
#pragma unroll
        for (int i = 0; i < 4; ++i) {
            int r = w * 32 + i * 8 + lr;
            int g = sl ^ (r & 7);
            gll16(Arow + (size_t)r * D_ + kt * 64 + g * 8, &As[(w * 32 + i * 8) * 64]);
            gll16(Brow + (size_t)r * D_ + kt * 64 + g * 8, &Bs[(w * 32 + i * 8) * 64]);
        }
        __syncthreads();
#pragma unroll
        for (int ks = 0; ks < 2; ++ks) {
            int kg = ks * 4 + (l >> 4);
            bf16x8 af[4], bfr[4];
#pragma unroll
            for (int ms = 0; ms < 4; ++ms) {
                int m = wm_ * 64 + ms * 16 + (l & 15);
                af[ms] = *(const bf16x8*)&As[m * 64 + (kg ^ (m & 7)) * 8];
            }
#pragma unroll
            for (int ns = 0; ns < 4; ++ns) {
                int n = wn * 64 + ns * 16 + (l & 15);
                bfr[ns] = *(const bf16x8*)&Bs[n * 64 + (kg ^ (n & 7)) * 8];
            }
#pragma unroll
            for (int ms = 0; ms < 4; ++ms)
#pragma unroll
                for (int ns = 0; ns < 4; ++ns)
                    acc[ms][ns] = __builtin_amdgcn_mfma_f32_16x16x32_bf16(af[ms], bfr[ns], acc[ms][ns], 0, 0, 0);
        }
    }
    float bv = bias[0];
#pragma unroll
    for (int ms = 0; ms < 4; ++ms) {
        int cb = c0 + wm_ * 64 + ms * 16 + (l >> 4) * 4;
#pragma unroll
        for (int ns = 0; ns < 4; ++ns) {
            int q = q0 + wn * 64 + ns * 16 + (l & 15);
            float s1v = s1[b * LQ + q] + bv;
#pragma unroll
            for (int r = 0; r < 4; ++r) {
                int c = cb + r;
                S16[((size_t)b * LC + c) * LQ + q] = (_Float16)(acc[ms][ns][r] + s0[b * LC + c] + s1v);
            }
        }
    }
}

// ---------- K2 (runs AFTER colstats+V2): row softmax, IN PLACE.
// S16 row (f16) -> P1 row (bf16) = qmask * exp(S - rowmax) / rowsum.
// One wave per row: 64 lanes x 8 elems = 512 = LQ. ----------
__global__ void k_rowsoftmax(_Float16* __restrict__ S16, const int* __restrict__ Qmask) {
    int row = blockIdx.x * 4 + (threadIdx.x >> 6);
    int lane = threadIdx.x & 63;
    int b = row / LC;
    _Float16* Sp = S16 + (size_t)row * LQ + lane * 8;
    f16x8 v = *(const f16x8*)Sp;
    const int* qm = Qmask + b * LQ + lane * 8;
    int4 m0 = *(const int4*)qm;
    int4 m1 = *(const int4*)(qm + 4);
    int mk[8] = {m0.x, m0.y, m0.z, m0.w, m1.x, m1.y, m1.z, m1.w};
    float vf[8];
#pragma unroll
    for (int k = 0; k < 8; ++k) vf[k] = (float)v[k];
    float mx = NEGINF;
#pragma unroll
    for (int k = 0; k < 8; ++k) if (mk[k]) mx = fmaxf(mx, vf[k]);
#pragma unroll
    for (int off = 32; off > 0; off >>= 1) mx = fmaxf(mx, __shfl_xor(mx, off, 64));
    float e[8];
    float s = 0.f;
#pragma unroll
    for (int k = 0; k < 8; ++k) { e[k] = __expf(vf[k] - mx); if (mk[k]) s += e[k]; }
#pragma unroll
    for (int off = 32; off > 0; off >>= 1) s += __shfl_xor(s, off, 64);
    float ri = 1.0f / s;
    unsigned short u[8];
#pragma unroll
    for (int k = 0; k < 8; ++k) u[k] = mk[k] ? bf16rne(e[k] * ri) : (unsigned short)0;
    *(us8*)Sp = *(const us8*)&u[0];   // overwrite in place as bf16
}

// ---------- K3a: col stats partials. grid (LQ/64, B, CCH); thread: (ql, cg) handles 32 c's ----------
__global__ __launch_bounds__(256) void k_colstats_part(const _Float16* __restrict__ S16,
                                                       const int* __restrict__ Cmask,
                                                       float* __restrict__ pm,
                                                       float* __restrict__ pl) {
    int b = blockIdx.y;
    int q0 = blockIdx.x * 64;
    int ch = blockIdx.z;
    int t = threadIdx.x, ql = t & 63, cg = t >> 6;
    const int cbase = ch * (LC / CCH);              // 128 c per chunk
    const _Float16* Sb = S16 + (size_t)b * LC * LQ + (size_t)cbase * LQ + q0 + ql;
    const int* cm = Cmask + b * LC + cbase;
    float v[32];
#pragma unroll
    for (int i = 0; i < 32; ++i) {
        int c = cg + 4 * i;
        float x = (float)Sb[(size_t)c * LQ];
        v[i] = cm[c] ? x : NEGINF;
    }
    float m8[8];
#pragma unroll
    for (int j = 0; j < 8; ++j) m8[j] = v[j];
#pragma unroll
    for (int i = 8; i < 32; ++i) m8[i & 7] = fmaxf(m8[i & 7], v[i]);
    float m = fmaxf(fmaxf(fmaxf(m8[0], m8[1]), fmaxf(m8[2], m8[3])),
                    fmaxf(fmaxf(m8[4], m8[5]), fmaxf(m8[6], m8[7])));
    float s8[8];
#pragma unroll
    for (int j = 0; j < 8; ++j) s8[j] = 0.f;
#pragma unroll
    for (int i = 0; i < 32; ++i) s8[i & 7] += __expf(v[i] - m);
    float l = ((s8[0] + s8[1]) + (s8[2] + s8[3])) + ((s8[4] + s8[5]) + (s8[6] + s8[7]));
    if (m == NEGINF) l = 0.f;
    __shared__ float Ms[4][64], Ls[4][64];
    Ms[cg][ql] = m; Ls[cg][ql] = l;
    __syncthreads();
    if (t < 64) {
        float mm = Ms[0][ql], ll = Ls[0][ql];
#pragma unroll
        for (int g = 1; g < 4; ++g) {
            float m2 = Ms[g][ql], l2 = Ls[g][ql];
            float mn = fmaxf(mm, m2);
            ll = ll * __expf(mm - mn) + l2 * __expf(m2 - mn);
            mm = mn;
        }
        size_t o = ((size_t)ch * B_ + b) * LQ + q0 + ql;
        pm[o] = mm; pl[o] = ll;
    }
}

// ---------- K3b: combine CCH partials per column ----------
__global__ void k_colstats_comb(const float* __restrict__ pm, const float* __restrict__ pl,
                                float* __restrict__ colmax, float* __restrict__ colsum) {
    int idx = blockIdx.x * 256 + threadIdx.x;       // b*LQ + q
    float m = NEGINF, l = 0.f;
#pragma unroll
    for (int ch = 0; ch < CCH; ++ch) {
        float m2 = pm[(size_t)ch * B_ * LQ + idx];
        float l2 = pl[(size_t)ch * B_ * LQ + idx];
        float mn = fmaxf(m, m2);
        l = l * __expf(m - mn) + l2 * __expf(m2 - mn);
        m = mn;
    }
    colmax[idx] = m; colsum[idx] = l;
}

// ---------- K5: Wf[128+dd][q] = bf16( (1/colsum[q]) * sum_c Cb16[dd][c]*cm[c]*exp(S[c][q]-colmax[q]) ) ----------
__global__ __launch_bounds__(256) void k_V2_mfma(const short* __restrict__ Cb16,
                                                 const _Float16* __restrict__ S16,
                                                 const int* __restrict__ Cmask,
                                                 const float* __restrict__ colmax,
                                                 const float* __restrict__ colsum,
                                                 short* __restrict__ Wf) {
    int b = blockIdx.y;
    int q0 = blockIdx.x * 64;
    int t = threadIdx.x, w = t >> 6, l = t & 63;
    __shared__ short As[128 * 64];
    __shared__ short Bs[64 * 72];
    f32x4 acc[2][4] = {};
    const short* Arow = Cb16 + (size_t)b * D_ * LC;
    int lr = l >> 3, sl = l & 7;
    float cmx[16];
#pragma unroll
    for (int j2 = 0; j2 < 4; ++j2)
        *(float4*)&cmx[j2 * 4] = *(const float4*)(colmax + b * LQ + q0 + w * 16 + j2 * 4);
    const _Float16* Sq = S16 + (size_t)b * LC * LQ + q0 + w * 16;
    const int* cmb = Cmask + b * LC;

    for (int kt = 0; kt < 32; ++kt) {
        int ck = kt * 64;
        __syncthreads();
#pragma unroll
        for (int i = 0; i < 4; ++i) {
            int r = w * 32 + i * 8 + lr;
            int g = sl ^ (r & 7);
            gll16(Arow + (size_t)r * LC + ck + g * 8, &As[(w * 32 + i * 8) * 64]);
        }
        {
            float cmf = (float)cmb[ck + l];
            const _Float16* sp = Sq + (size_t)(ck + l) * LQ;
            f16x8 v0 = *(const f16x8*)sp;
            f16x8 v1 = *(const f16x8*)(sp + 8);
#pragma unroll
            for (int j = 0; j < 8; ++j)
                Bs[(w * 16 + j) * 72 + l] = (short)bf16rne(cmf * __expf((float)v0[j] - cmx[j]));
#pragma unroll
            for (int j = 0; j < 8; ++j)
                Bs[(w * 16 + 8 + j) * 72 + l] = (short)bf16rne(cmf * __expf((float)v1[j] - cmx[8 + j]));
        }
        __syncthreads();
#pragma unroll
        for (int ks = 0; ks < 2; ++ks) {
            int kg = ks * 4 + (l >> 4);
            bf16x8 af[2], bfr[4];
#pragma unroll
            for (int ms = 0; ms < 2; ++ms) {
                int m = w * 32 + ms * 16 + (l & 15);
                af[ms] = *(const bf16x8*)&As[m * 64 + (kg ^ (m & 7)) * 8];
            }
#pragma unroll
            for (int ns = 0; ns < 4; ++ns) {
                int n = ns * 16 + (l & 15);
                bfr[ns] = *(const bf16x8*)&Bs[n * 72 + kg * 8];
            }
#pragma unroll
            for (int ms = 0; ms < 2; ++ms)
#pragma unroll
                for (int ns = 0; ns < 4; ++ns)
                    acc[ms][ns] = __builtin_amdgcn_mfma_f32_16x16x32_bf16(af[ms], bfr[ns], acc[ms][ns], 0, 0, 0);
        }
    }
#pragma unroll
    for (int ms = 0; ms < 2; ++ms)
#pragma unroll
        for (int ns = 0; ns < 4; ++ns) {
            int q = q0 + ns * 16 + (l & 15);
            float csi = 1.0f / colsum[b * LQ + q];
#pragma unroll
            for (int r = 0; r < 4; ++r) {
                int dd = w * 32 + ms * 16 + (l >> 4) * 4 + r;
                Wf[((size_t)b * 256 + 128 + dd) * LQ + q] = (short)bf16rne(acc[ms][ns][r] * csi);
            }
        }
}

// ---------- K6: OUT^T GEMM — now a pure bf16 GEMM: acc[c][n] = sum_q P1[c][q]*Wf[n][q].
// A = Wf rows (nT*128..+128), B = P1 rows (c0..c0+128); both gll16-staged, XOR-swizzled.
// Epilogue also writes out plane 0 (= C) when nT==0, replacing k_copy. ----------
__global__ __launch_bounds__(256) void k_out_mfma(const short* __restrict__ P1,
                                                  const short* __restrict__ Wf,
                                                  const float* __restrict__ C,
                                                  float* __restrict__ out) {
    int b = blockIdx.y;
    int cT = blockIdx.x >> 1, nT = blockIdx.x & 1;
    int c0 = cT * 128;
    int t = threadIdx.x, w = t >> 6, l = t & 63;
    int wm_ = w >> 1, wc = w & 1;
    __shared__ short As[128 * 64];
    __shared__ short Bs[128 * 64];
    f32x4 acc[4][4] = {};
    const short* Arow = Wf + ((size_t)b * 256 + nT * 128) * LQ;
    const short* Brow = P1 + ((size_t)b * LC + c0) * LQ;
    int lr = l >> 3, sl = l & 7;
    for (int kt = 0; kt < 8; ++kt) {
        __syncthreads();
#pragma unroll
        for (int i = 0; i < 4; ++i) {
            int r = w * 32 + i * 8 + lr;
            int g = sl ^ (r & 7);
            gll16(Arow + (size_t)r * LQ + kt * 64 + g * 8, &As[(w * 32 + i * 8) * 64]);
            gll16(Brow + (size_t)r * LQ + kt * 64 + g * 8, &Bs[(w * 32 + i * 8) * 64]);
        }
        __syncthreads();
#pragma unroll
        for (int ks = 0; ks < 2; ++ks) {
            int kg = ks * 4 + (l >> 4);
            bf16x8 af[4], bfr[4];
#pragma unroll
            for (int ms = 0; ms < 4; ++ms) {
                int m = wm_ * 64 + ms * 16 + (l & 15);
                af[ms] = *(const bf16x8*)&As[m * 64 + (kg ^ (m & 7)) * 8];
            }
#pragma unroll
            for (int ns = 0; ns < 4; ++ns) {
                int cc = wc * 64 + ns * 16 + (l & 15);
                bfr[ns] = *(const bf16x8*)&Bs[cc * 64 + (kg ^ (cc & 7)) * 8];
            }
#pragma unroll
            for (int ms = 0; ms < 4; ++ms)
#pragma unroll
                for (int ns = 0; ns < 4; ++ns)
                    acc[ms][ns] = __builtin_amdgcn_mfma_f32_16x16x32_bf16(af[ms], bfr[ns], acc[ms][ns], 0, 0, 0);
        }
    }
#pragma unroll
    for (int ms = 0; ms < 4; ++ms) {
        int nb = nT * 128 + wm_ * 64 + ms * 16 + (l >> 4) * 4;
#pragma unroll
        for (int ns = 0; ns < 4; ++ns) {
            int c = c0 + wc * 64 + ns * 16 + (l & 15);
#pragma unroll
            for (int r = 0; r < 4; ++r) {
                int n = nb + r;
                float a = acc[ms][ns][r];
                if (n < 128) {
                    float cv = C[((size_t)b * D_ + n) * LC + c];
                    out[((size_t)b * 512 + n) * LC + c] = cv;          // plane 0: Ct (replaces k_copy)
                    out[((size_t)b * 512 + 128 + n) * LC + c] = a;     // plane 1: A
                    out[((size_t)b * 512 + 256 + n) * LC + c] = cv * a;// plane 2: Ct*A
                } else {
                    int dd = n - 128;
                    float cv = C[((size_t)b * D_ + dd) * LC + c];
                    out[((size_t)b * 512 + 384 + dd) * LC + c] = cv * a;// plane 3: Ct*Bm
                }
            }
        }
    }
}

extern "C" void kernel_launch(void* const* d_in, const int* in_sizes, int n_in,
                              void* d_out, int out_size, void* d_ws, size_t ws_size,
                              hipStream_t stream) {
    const float* C     = (const float*)d_in[0];
    const float* Q     = (const float*)d_in[1];
    const int*   Cmask = (const int*)d_in[2];
    const int*   Qmask = (const int*)d_in[3];
    const float* w_c   = (const float*)d_in[4];
    const float* w_q   = (const float*)d_in[5];
    const float* w_mul = (const float*)d_in[6];
    const float* bias  = (const float*)d_in[7];
    float* out = (float*)d_out;

    // workspace layout: ~116.3 MB total (unchanged; P1 reuses S16 in place)
    _Float16* S16 = (_Float16*)d_ws;                      // B*LC*LQ fp16  = 67.1 MB (later: P1 bf16 in place)
    short* Cb16 = (short*)(S16 + (size_t)B_ * LC * LQ);   // B*D*LC bf16   = 16.8 MB
    short* Ctw  = Cb16 + (size_t)B_ * D_ * LC;            // B*LC*D bf16   = 16.8 MB
    short* Qt16 = Ctw + (size_t)B_ * LC * D_;             // B*LQ*D bf16   =  4.2 MB
    short* Wf   = Qt16 + (size_t)B_ * LQ * D_;            // B*256*LQ bf16 =  8.4 MB
    float* s0     = (float*)(Wf + (size_t)B_ * 256 * LQ); // B*LC
    float* s1     = s0 + B_ * LC;                         // B*LQ
    float* rowmax = s1 + B_ * LQ;                         // B*LC (unused now, kept for layout)
    float* rowsum = rowmax + B_ * LC;                     // B*LC (unused now, kept for layout)
    float* colmax = rowsum + B_ * LC;                     // B*LQ
    float* colsum = colmax + B_ * LQ;                     // B*LQ
    float* pm     = colsum + B_ * LQ;                     // CCH*B*LQ = 1 MB
    float* pl     = pm + (size_t)CCH * B_ * LQ;           // CCH*B*LQ = 1 MB
    (void)rowmax; (void)rowsum;

    hipLaunchKernelGGL(k_dotw, dim3(B_ * LC / 256), dim3(256), 0, stream, C, w_c, s0, LC);
    hipLaunchKernelGGL(k_dotw, dim3(B_ * LQ / 256), dim3(256), 0, stream, Q, w_q, s1, LQ);
    hipLaunchKernelGGL(k_prep_C, dim3(LC / 64, B_), dim3(256), 0, stream, C, w_mul, Ctw, Cb16);
    hipLaunchKernelGGL(k_prep_Q, dim3(LQ / 64, B_), dim3(256), 0, stream, Q, Qt16, Wf);
    hipLaunchKernelGGL(k_S_mfma, dim3((LC / 128) * (LQ / 128), B_), dim3(256), 0, stream,
                       Ctw, Qt16, s0, s1, bias, S16);
    // col-softmax consumers of RAW S first...
    hipLaunchKernelGGL(k_colstats_part, dim3(LQ / 64, B_, CCH), dim3(256), 0, stream,
                       S16, Cmask, pm, pl);
    hipLaunchKernelGGL(k_colstats_comb, dim3(B_ * LQ / 256), dim3(256), 0, stream,
                       pm, pl, colmax, colsum);
    hipLaunchKernelGGL(k_V2_mfma, dim3(LQ / 64, B_), dim3(256), 0, stream,
                       Cb16, S16, Cmask, colmax, colsum, Wf);
    // ...then overwrite S in place with row-softmax P1 (bf16)
    hipLaunchKernelGGL(k_rowsoftmax, dim3(B_ * LC / 4), dim3(256), 0, stream, S16, Qmask);
    hipLaunchKernelGGL(k_out_mfma, dim3((LC / 128) * 2, B_), dim3(256), 0, stream,
                       (const short*)S16, Wf, C, out);
}

// Round 2
// 411.614 us; speedup vs baseline: 1.0417x; 1.0013x over previous
//
#include <hip/hip_runtime.h>

#define B_ 32
#define D_ 128
#define LC 2048
#define LQ 512
#define CCH 16   // c-chunks for colstats partials

#define NEGINF (-3.0e38f)

typedef __attribute__((ext_vector_type(8))) short bf16x8;
typedef __attribute__((ext_vector_type(4))) float f32x4;
typedef __attribute__((ext_vector_type(8))) unsigned short us8;
typedef __attribute__((ext_vector_type(8))) _Float16 f16x8;

__device__ __forceinline__ unsigned short bf16rne(float x) {
    unsigned int u = __float_as_uint(x);
    u = (u + 0x7FFFu + ((u >> 16) & 1u)) >> 16;
    return (unsigned short)u;
}

__device__ __forceinline__ void gll16(const void* g, void* l) {
    __builtin_amdgcn_global_load_lds((const __attribute__((address_space(1))) void*)g,
                                     (__attribute__((address_space(3))) void*)l, 16, 0, 0);
}

// ---------- K0: outv[b,x] = sum_d X[b,d,x] * w[d] ----------
__global__ void k_dotw(const float* __restrict__ X, const float* __restrict__ w,
                       float* __restrict__ outv, int L) {
    int idx = blockIdx.x * 256 + threadIdx.x;
    int b = idx / L, x = idx - b * L;
    const float* Xp = X + (size_t)b * D_ * L + x;
    float acc = 0.f;
#pragma unroll 8
    for (int dd = 0; dd < D_; ++dd) acc += Xp[(size_t)dd * L] * w[dd];
    outv[idx] = acc;
}

// ---------- prep C: Ctw[c][d] = bf16(C[d][c]*wmul[d]) (transposed), Cb16[d][c] = bf16(C[d][c]) ----------
__global__ void k_prep_C(const float* __restrict__ C, const float* __restrict__ wmul,
                         short* __restrict__ Ctw, short* __restrict__ Cb16) {
    int b = blockIdx.y, c0 = blockIdx.x * 64;
    __shared__ float Tf[128][65];
    __shared__ float wm[128];
    int t = threadIdx.x;
    if (t < 128) wm[t] = wmul[t];
    const float* Cb = C + (size_t)b * D_ * LC;
#pragma unroll
    for (int i = 0; i < 8; ++i) {
        int idx = t + i * 256;
        int d = idx >> 4, c4 = idx & 15;
        float4 v = *(const float4*)(Cb + (size_t)d * LC + c0 + c4 * 4);
        Tf[d][c4 * 4 + 0] = v.x; Tf[d][c4 * 4 + 1] = v.y;
        Tf[d][c4 * 4 + 2] = v.z; Tf[d][c4 * 4 + 3] = v.w;
        ushort4 cv;
        cv.x = bf16rne(v.x); cv.y = bf16rne(v.y); cv.z = bf16rne(v.z); cv.w = bf16rne(v.w);
        *(ushort4*)(Cb16 + ((size_t)b * D_ + d) * LC + c0 + c4 * 4) = cv;
    }
    __syncthreads();
    int c_l = t & 63, g = t >> 6;
    unsigned short u[32];
#pragma unroll
    for (int j = 0; j < 32; ++j) {
        int d = g * 32 + j;
        u[j] = bf16rne(Tf[d][c_l] * wm[d]);
    }
    short* dst = Ctw + ((size_t)b * LC + c0 + c_l) * D_ + g * 32;
#pragma unroll
    for (int k = 0; k < 4; ++k) *(us8*)(dst + k * 8) = *(const us8*)&u[k * 8];
}

// ---------- prep Q: Qt16[q][d] = bf16(Q[d][q]) (transposed), W[n=d][q] = bf16(Q[d][q]) ----------
__global__ void k_prep_Q(const float* __restrict__ Q, short* __restrict__ Qt16,
                         short* __restrict__ Wf) {
    int b = blockIdx.y, q0 = blockIdx.x * 64;
    __shared__ float Tf[128][65];
    int t = threadIdx.x;
    const float* Qb = Q + (size_t)b * D_ * LQ;
#pragma unroll
    for (int i = 0; i < 8; ++i) {
        int idx = t + i * 256;
        int d = idx >> 4, q4 = idx & 15;
        float4 v = *(const float4*)(Qb + (size_t)d * LQ + q0 + q4 * 4);
        Tf[d][q4 * 4 + 0] = v.x; Tf[d][q4 * 4 + 1] = v.y;
        Tf[d][q4 * 4 + 2] = v.z; Tf[d][q4 * 4 + 3] = v.w;
        ushort4 cv;
        cv.x = bf16rne(v.x); cv.y = bf16rne(v.y); cv.z = bf16rne(v.z); cv.w = bf16rne(v.w);
        *(ushort4*)(Wf + ((size_t)b * 256 + d) * LQ + q0 + q4 * 4) = cv;
    }
    __syncthreads();
    int q_l = t & 63, g = t >> 6;
    unsigned short u[32];
#pragma unroll
    for (int j = 0; j < 32; ++j) u[j] = bf16rne(Tf[g * 32 + j][q_l]);
    short* dst = Qt16 + ((size_t)b * LQ + q0 + q_l) * D_ + g * 32;
#pragma unroll
    for (int k = 0; k < 4; ++k) *(us8*)(dst + k * 8) = *(const us8*)&u[k * 8];
}

// ---------- K1: S[c][q] via MFMA, stored fp16 ----------
__global__ __launch_bounds__(256) void k_S_mfma(const short* __restrict__ Ctw,
                                                const short* __restrict__ Qt16,
                                                const float* __restrict__ s0,
                                                const float* __restrict__ s1,
                                                const float* __restrict__ bias,
                                                _Float16* __restrict__ S16) {
    int b = blockIdx.y;
    int cT = blockIdx.x >> 2, qT = blockIdx.x & 3;
    int c0 = cT * 128, q0 = qT * 128;
    int t = threadIdx.x, w = t >> 6, l = t & 63;
    int wm_ = w >> 1, wn = w & 1;
    __shared__ short As[128 * 64];
    __shared__ short Bs[128 * 64];
    f32x4 acc[4][4] = {};
    const short* Arow = Ctw + ((size_t)b * LC + c0) * D_;
    const short* Brow = Qt16 + ((size_t)b * LQ + q0) * D_;
    int lr = l >> 3, sl = l & 7;
    for (int kt = 0; kt < 2; ++kt) {
        __syncthreads();
#pragma unroll
        for (int i = 0; i < 4; ++i) {
            int r = w * 32 + i * 8 + lr;
            int g = sl ^ (r & 7);
            gll16(Arow + (size_t)r * D_ + kt * 64 + g * 8, &As[(w * 32 + i * 8) * 64]);
            gll16(Brow + (size_t)r * D_ + kt * 64 + g * 8, &Bs[(w * 32 + i * 8) * 64]);
        }
        __syncthreads();
#pragma unroll
        for (int ks = 0; ks < 2; ++ks) {
            int kg = ks * 4 + (l >> 4);
            bf16x8 af[4], bfr[4];
#pragma unroll
            for (int ms = 0; ms < 4; ++ms) {
                int m = wm_ * 64 + ms * 16 + (l & 15);
                af[ms] = *(const bf16x8*)&As[m * 64 + (kg ^ (m & 7)) * 8];
            }
#pragma unroll
            for (int ns = 0; ns < 4; ++ns) {
                int n = wn * 64 + ns * 16 + (l & 15);
                bfr[ns] = *(const bf16x8*)&Bs[n * 64 + (kg ^ (n & 7)) * 8];
            }
#pragma unroll
            for (int ms = 0; ms < 4; ++ms)
#pragma unroll
                for (int ns = 0; ns < 4; ++ns)
                    acc[ms][ns] = __builtin_amdgcn_mfma_f32_16x16x32_bf16(af[ms], bfr[ns], acc[ms][ns], 0, 0, 0);
        }
    }
    float bv = bias[0];
#pragma unroll
    for (int ms = 0; ms < 4; ++ms) {
        int cb = c0 + wm_ * 64 + ms * 16 + (l >> 4) * 4;
#pragma unroll
        for (int ns = 0; ns < 4; ++ns) {
            int q = q0 + wn * 64 + ns * 16 + (l & 15);
            float s1v = s1[b * LQ + q] + bv;
#pragma unroll
            for (int r = 0; r < 4; ++r) {
                int c = cb + r;
                S16[((size_t)b * LC + c) * LQ + q] = (_Float16)(acc[ms][ns][r] + s0[b * LC + c] + s1v);
            }
        }
    }
}

// ---------- K2 (runs AFTER colstats+V2): row softmax, IN PLACE.
// S16 row (f16) -> P1 row (bf16) = qmask * exp(S - rowmax) / rowsum. ----------
__global__ void k_rowsoftmax(_Float16* __restrict__ S16, const int* __restrict__ Qmask) {
    int row = blockIdx.x * 4 + (threadIdx.x >> 6);
    int lane = threadIdx.x & 63;
    int b = row / LC;
    _Float16* Sp = S16 + (size_t)row * LQ + lane * 8;
    f16x8 v = *(const f16x8*)Sp;
    const int* qm = Qmask + b * LQ + lane * 8;
    int4 m0 = *(const int4*)qm;
    int4 m1 = *(const int4*)(qm + 4);
    int mk[8] = {m0.x, m0.y, m0.z, m0.w, m1.x, m1.y, m1.z, m1.w};
    float vf[8];
#pragma unroll
    for (int k = 0; k < 8; ++k) vf[k] = (float)v[k];
    float mx = NEGINF;
#pragma unroll
    for (int k = 0; k < 8; ++k) if (mk[k]) mx = fmaxf(mx, vf[k]);
#pragma unroll
    for (int off = 32; off > 0; off >>= 1) mx = fmaxf(mx, __shfl_xor(mx, off, 64));
    float e[8];
    float s = 0.f;
#pragma unroll
    for (int k = 0; k < 8; ++k) { e[k] = __expf(vf[k] - mx); if (mk[k]) s += e[k]; }
#pragma unroll
    for (int off = 32; off > 0; off >>= 1) s += __shfl_xor(s, off, 64);
    float ri = 1.0f / s;
    unsigned short u[8];
#pragma unroll
    for (int k = 0; k < 8; ++k) u[k] = mk[k] ? bf16rne(e[k] * ri) : (unsigned short)0;
    *(us8*)Sp = *(const us8*)&u[0];   // overwrite in place as bf16
}

// ---------- K3a: col stats partials ----------
__global__ __launch_bounds__(256) void k_colstats_part(const _Float16* __restrict__ S16,
                                                       const int* __restrict__ Cmask,
                                                       float* __restrict__ pm,
                                                       float* __restrict__ pl) {
    int b = blockIdx.y;
    int q0 = blockIdx.x * 64;
    int ch = blockIdx.z;
    int t = threadIdx.x, ql = t & 63, cg = t >> 6;
    const int cbase = ch * (LC / CCH);              // 128 c per chunk
    const _Float16* Sb = S16 + (size_t)b * LC * LQ + (size_t)cbase * LQ + q0 + ql;
    const int* cm = Cmask + b * LC + cbase;
    float v[32];
#pragma unroll
    for (int i = 0; i < 32; ++i) {
        int c = cg + 4 * i;
        float x = (float)Sb[(size_t)c * LQ];
        v[i] = cm[c] ? x : NEGINF;
    }
    float m8[8];
#pragma unroll
    for (int j = 0; j < 8; ++j) m8[j] = v[j];
#pragma unroll
    for (int i = 8; i < 32; ++i) m8[i & 7] = fmaxf(m8[i & 7], v[i]);
    float m = fmaxf(fmaxf(fmaxf(m8[0], m8[1]), fmaxf(m8[2], m8[3])),
                    fmaxf(fmaxf(m8[4], m8[5]), fmaxf(m8[6], m8[7])));
    float s8[8];
#pragma unroll
    for (int j = 0; j < 8; ++j) s8[j] = 0.f;
#pragma unroll
    for (int i = 0; i < 32; ++i) s8[i & 7] += __expf(v[i] - m);
    float l = ((s8[0] + s8[1]) + (s8[2] + s8[3])) + ((s8[4] + s8[5]) + (s8[6] + s8[7]));
    if (m == NEGINF) l = 0.f;
    __shared__ float Ms[4][64], Ls[4][64];
    Ms[cg][ql] = m; Ls[cg][ql] = l;
    __syncthreads();
    if (t < 64) {
        float mm = Ms[0][ql], ll = Ls[0][ql];
#pragma unroll
        for (int g = 1; g < 4; ++g) {
            float m2 = Ms[g][ql], l2 = Ls[g][ql];
            float mn = fmaxf(mm, m2);
            ll = ll * __expf(mm - mn) + l2 * __expf(m2 - mn);
            mm = mn;
        }
        size_t o = ((size_t)ch * B_ + b) * LQ + q0 + ql;
        pm[o] = mm; pl[o] = ll;
    }
}

// ---------- K3b: combine CCH partials per column ----------
__global__ void k_colstats_comb(const float* __restrict__ pm, const float* __restrict__ pl,
                                float* __restrict__ colmax, float* __restrict__ colsum) {
    int idx = blockIdx.x * 256 + threadIdx.x;       // b*LQ + q
    float m = NEGINF, l = 0.f;
#pragma unroll
    for (int ch = 0; ch < CCH; ++ch) {
        float m2 = pm[(size_t)ch * B_ * LQ + idx];
        float l2 = pl[(size_t)ch * B_ * LQ + idx];
        float mn = fmaxf(m, m2);
        l = l * __expf(m - mn) + l2 * __expf(m2 - mn);
        m = mn;
    }
    colmax[idx] = m; colsum[idx] = l;
}

// ---------- K5: Wf[128+dd][q] = bf16( (1/colsum[q]) * sum_c Cb16[dd][c]*cm[c]*exp(S[c][q]-colmax[q]) ) ----------
__global__ __launch_bounds__(256) void k_V2_mfma(const short* __restrict__ Cb16,
                                                 const _Float16* __restrict__ S16,
                                                 const int* __restrict__ Cmask,
                                                 const float* __restrict__ colmax,
                                                 const float* __restrict__ colsum,
                                                 short* __restrict__ Wf) {
    int b = blockIdx.y;
    int q0 = blockIdx.x * 64;
    int t = threadIdx.x, w = t >> 6, l = t & 63;
    __shared__ short As[128 * 64];
    __shared__ short Bs[64 * 72];
    f32x4 acc[2][4] = {};
    const short* Arow = Cb16 + (size_t)b * D_ * LC;
    int lr = l >> 3, sl = l & 7;
    float cmx[16];
#pragma unroll
    for (int j2 = 0; j2 < 4; ++j2)
        *(float4*)&cmx[j2 * 4] = *(const float4*)(colmax + b * LQ + q0 + w * 16 + j2 * 4);
    const _Float16* Sq = S16 + (size_t)b * LC * LQ + q0 + w * 16;
    const int* cmb = Cmask + b * LC;

    for (int kt = 0; kt < 32; ++kt) {
        int ck = kt * 64;
        __syncthreads();
#pragma unroll
        for (int i = 0; i < 4; ++i) {
            int r = w * 32 + i * 8 + lr;
            int g = sl ^ (r & 7);
            gll16(Arow + (size_t)r * LC + ck + g * 8, &As[(w * 32 + i * 8) * 64]);
        }
        {
            float cmf = (float)cmb[ck + l];
            const _Float16* sp = Sq + (size_t)(ck + l) * LQ;
            f16x8 v0 = *(const f16x8*)sp;
            f16x8 v1 = *(const f16x8*)(sp + 8);
#pragma unroll
            for (int j = 0; j < 8; ++j)
                Bs[(w * 16 + j) * 72 + l] = (short)bf16rne(cmf * __expf((float)v0[j] - cmx[j]));
#pragma unroll
            for (int j = 0; j < 8; ++j)
                Bs[(w * 16 + 8 + j) * 72 + l] = (short)bf16rne(cmf * __expf((float)v1[j] - cmx[8 + j]));
        }
        __syncthreads();
#pragma unroll
        for (int ks = 0; ks < 2; ++ks) {
            int kg = ks * 4 + (l >> 4);
            bf16x8 af[2], bfr[4];
#pragma unroll
            for (int ms = 0; ms < 2; ++ms) {
                int m = w * 32 + ms * 16 + (l & 15);
                af[ms] = *(const bf16x8*)&As[m * 64 + (kg ^ (m & 7)) * 8];
            }
#pragma unroll
            for (int ns = 0; ns < 4; ++ns) {
                int n = ns * 16 + (l & 15);
                bfr[ns] = *(const bf16x8*)&Bs[n * 72 + kg * 8];
            }
#pragma unroll
            for (int ms = 0; ms < 2; ++ms)
#pragma unroll
                for (int ns = 0; ns < 4; ++ns)
                    acc[ms][ns] = __builtin_amdgcn_mfma_f32_16x16x32_bf16(af[ms], bfr[ns], acc[ms][ns], 0, 0, 0);
        }
    }
#pragma unroll
    for (int ms = 0; ms < 2; ++ms)
#pragma unroll
        for (int ns = 0; ns < 4; ++ns) {
            int q = q0 + ns * 16 + (l & 15);
            float csi = 1.0f / colsum[b * LQ + q];
#pragma unroll
            for (int r = 0; r < 4; ++r) {
                int dd = w * 32 + ms * 16 + (l >> 4) * 4 + r;
                Wf[((size_t)b * 256 + 128 + dd) * LQ + q] = (short)bf16rne(acc[ms][ns][r] * csi);
            }
        }
}

// ---------- K6: OUT^T GEMM, merged-nT: one 512-thread block computes full 256n x 128c tile.
// acc[c][n] = sum_q P1[c][q]*Wf[n][q]. A = all 256 Wf rows, B = 128 P1 rows.
// P1 fetched ONCE per c-tile (was twice). Epilogue writes all 4 out planes. ----------
__global__ __launch_bounds__(512, 4) void k_out_mfma(const short* __restrict__ P1,
                                                     const short* __restrict__ Wf,
                                                     const float* __restrict__ C,
                                                     float* __restrict__ out) {
    int b = blockIdx.y;
    int c0 = blockIdx.x * 128;
    int t = threadIdx.x, w = t >> 6, l = t & 63;
    int wn = w & 3, wc = w >> 2;           // wave tile: n = wn*64.., c = wc*64..
    __shared__ short As[256 * 64];          // Wf rows (n), 32 KB
    __shared__ short Bs[128 * 64];          // P1 rows (c), 16 KB
    f32x4 acc[4][4] = {};
    const short* Arow = Wf + (size_t)b * 256 * LQ;
    const short* Brow = P1 + ((size_t)b * LC + c0) * LQ;
    int lr = l >> 3, sl = l & 7;
    for (int kt = 0; kt < 8; ++kt) {
        __syncthreads();
#pragma unroll
        for (int i = 0; i < 4; ++i) {       // As: 8 waves x 4 iters x 8 rows = 256
            int r = w * 32 + i * 8 + lr;
            int g = sl ^ lr;
            gll16(Arow + (size_t)r * LQ + kt * 64 + g * 8, &As[(w * 32 + i * 8) * 64]);
        }
#pragma unroll
        for (int i = 0; i < 2; ++i) {       // Bs: 8 waves x 2 iters x 8 rows = 128
            int r = w * 16 + i * 8 + lr;
            int g = sl ^ lr;
            gll16(Brow + (size_t)r * LQ + kt * 64 + g * 8, &Bs[(w * 16 + i * 8) * 64]);
        }
        __syncthreads();
#pragma unroll
        for (int ks = 0; ks < 2; ++ks) {
            int kg = ks * 4 + (l >> 4);
            bf16x8 af[4], bfr[4];
#pragma unroll
            for (int ms = 0; ms < 4; ++ms) {
                int m = wn * 64 + ms * 16 + (l & 15);
                af[ms] = *(const bf16x8*)&As[m * 64 + (kg ^ (m & 7)) * 8];
            }
#pragma unroll
            for (int ns = 0; ns < 4; ++ns) {
                int cc = wc * 64 + ns * 16 + (l & 15);
                bfr[ns] = *(const bf16x8*)&Bs[cc * 64 + (kg ^ (cc & 7)) * 8];
            }
#pragma unroll
            for (int ms = 0; ms < 4; ++ms)
#pragma unroll
                for (int ns = 0; ns < 4; ++ns)
                    acc[ms][ns] = __builtin_amdgcn_mfma_f32_16x16x32_bf16(af[ms], bfr[ns], acc[ms][ns], 0, 0, 0);
        }
    }
#pragma unroll
    for (int ms = 0; ms < 4; ++ms) {
        int nb = wn * 64 + ms * 16 + (l >> 4) * 4;
#pragma unroll
        for (int ns = 0; ns < 4; ++ns) {
            int c = c0 + wc * 64 + ns * 16 + (l & 15);
#pragma unroll
            for (int r = 0; r < 4; ++r) {
                int n = nb + r;
                float a = acc[ms][ns][r];
                if (n < 128) {
                    float cv = C[((size_t)b * D_ + n) * LC + c];
                    out[((size_t)b * 512 + n) * LC + c] = cv;          // plane 0: Ct
                    out[((size_t)b * 512 + 128 + n) * LC + c] = a;     // plane 1: A
                    out[((size_t)b * 512 + 256 + n) * LC + c] = cv * a;// plane 2: Ct*A
                } else {
                    int dd = n - 128;
                    float cv = C[((size_t)b * D_ + dd) * LC + c];
                    out[((size_t)b * 512 + 384 + dd) * LC + c] = cv * a;// plane 3: Ct*Bm
                }
            }
        }
    }
}

extern "C" void kernel_launch(void* const* d_in, const int* in_sizes, int n_in,
                              void* d_out, int out_size, void* d_ws, size_t ws_size,
                              hipStream_t stream) {
    const float* C     = (const float*)d_in[0];
    const float* Q     = (const float*)d_in[1];
    const int*   Cmask = (const int*)d_in[2];
    const int*   Qmask = (const int*)d_in[3];
    const float* w_c   = (const float*)d_in[4];
    const float* w_q   = (const float*)d_in[5];
    const float* w_mul = (const float*)d_in[6];
    const float* bias  = (const float*)d_in[7];
    float* out = (float*)d_out;

    _Float16* S16 = (_Float16*)d_ws;                      // B*LC*LQ fp16  = 67.1 MB (later: P1 bf16 in place)
    short* Cb16 = (short*)(S16 + (size_t)B_ * LC * LQ);   // B*D*LC bf16   = 16.8 MB
    short* Ctw  = Cb16 + (size_t)B_ * D_ * LC;            // B*LC*D bf16   = 16.8 MB
    short* Qt16 = Ctw + (size_t)B_ * LC * D_;             // B*LQ*D bf16   =  4.2 MB
    short* Wf   = Qt16 + (size_t)B_ * LQ * D_;            // B*256*LQ bf16 =  8.4 MB
    float* s0     = (float*)(Wf + (size_t)B_ * 256 * LQ); // B*LC
    float* s1     = s0 + B_ * LC;                         // B*LQ
    float* colmax = s1 + B_ * LQ;                         // B*LQ
    float* colsum = colmax + B_ * LQ;                     // B*LQ
    float* pm     = colsum + B_ * LQ;                     // CCH*B*LQ = 1 MB
    float* pl     = pm + (size_t)CCH * B_ * LQ;           // CCH*B*LQ = 1 MB

    hipLaunchKernelGGL(k_dotw, dim3(B_ * LC / 256), dim3(256), 0, stream, C, w_c, s0, LC);
    hipLaunchKernelGGL(k_dotw, dim3(B_ * LQ / 256), dim3(256), 0, stream, Q, w_q, s1, LQ);
    hipLaunchKernelGGL(k_prep_C, dim3(LC / 64, B_), dim3(256), 0, stream, C, w_mul, Ctw, Cb16);
    hipLaunchKernelGGL(k_prep_Q, dim3(LQ / 64, B_), dim3(256), 0, stream, Q, Qt16, Wf);
    hipLaunchKernelGGL(k_S_mfma, dim3((LC / 128) * (LQ / 128), B_), dim3(256), 0, stream,
                       Ctw, Qt16, s0, s1, bias, S16);
    // col-softmax consumers of RAW S first...
    hipLaunchKernelGGL(k_colstats_part, dim3(LQ / 64, B_, CCH), dim3(256), 0, stream,
                       S16, Cmask, pm, pl);
    hipLaunchKernelGGL(k_colstats_comb, dim3(B_ * LQ / 256), dim3(256), 0, stream,
                       pm, pl, colmax, colsum);
    hipLaunchKernelGGL(k_V2_mfma, dim3(LQ / 64, B_), dim3(256), 0, stream,
                       Cb16, S16, Cmask, colmax, colsum, Wf);
    // ...then overwrite S in place with row-softmax P1 (bf16)
    hipLaunchKernelGGL(k_rowsoftmax, dim3(B_ * LC / 4), dim3(256), 0, stream, S16, Qmask);
    hipLaunchKernelGGL(k_out_mfma, dim3(LC / 128, B_), dim3(512), 0, stream,
                       (const short*)S16, Wf, C, out);
}

// Round 4
// 389.950 us; speedup vs baseline: 1.0996x; 1.0556x over previous
//
#include <hip/hip_runtime.h>

#define B_ 32
#define D_ 128
#define LC 2048
#define LQ 512
#define CCH 16   // c-chunks for colstats partials == LC/128 (one per k_S c-tile)

#define NEGINF (-3.0e38f)

typedef __attribute__((ext_vector_type(8))) short bf16x8;
typedef __attribute__((ext_vector_type(4))) float f32x4;
typedef __attribute__((ext_vector_type(8))) unsigned short us8;
typedef __attribute__((ext_vector_type(8))) _Float16 f16x8;

__device__ __forceinline__ unsigned short bf16rne(float x) {
    unsigned int u = __float_as_uint(x);
    u = (u + 0x7FFFu + ((u >> 16) & 1u)) >> 16;
    return (unsigned short)u;
}

__device__ __forceinline__ void gll16(const void* g, void* l) {
    __builtin_amdgcn_global_load_lds((const __attribute__((address_space(1))) void*)g,
                                     (__attribute__((address_space(3))) void*)l, 16, 0, 0);
}

// ---------- K0: outv[b,x] = sum_d X[b,d,x] * w[d] ----------
__global__ void k_dotw(const float* __restrict__ X, const float* __restrict__ w,
                       float* __restrict__ outv, int L) {
    int idx = blockIdx.x * 256 + threadIdx.x;
    int b = idx / L, x = idx - b * L;
    const float* Xp = X + (size_t)b * D_ * L + x;
    float acc = 0.f;
#pragma unroll 8
    for (int dd = 0; dd < D_; ++dd) acc += Xp[(size_t)dd * L] * w[dd];
    outv[idx] = acc;
}

// ---------- prep C: Ctw[c][d] = bf16(C[d][c]*wmul[d]) (transposed), Cb16[d][c] = bf16(C[d][c]) ----------
__global__ void k_prep_C(const float* __restrict__ C, const float* __restrict__ wmul,
                         short* __restrict__ Ctw, short* __restrict__ Cb16) {
    int b = blockIdx.y, c0 = blockIdx.x * 64;
    __shared__ float Tf[128][65];
    __shared__ float wm[128];
    int t = threadIdx.x;
    if (t < 128) wm[t] = wmul[t];
    const float* Cb = C + (size_t)b * D_ * LC;
#pragma unroll
    for (int i = 0; i < 8; ++i) {
        int idx = t + i * 256;
        int d = idx >> 4, c4 = idx & 15;
        float4 v = *(const float4*)(Cb + (size_t)d * LC + c0 + c4 * 4);
        Tf[d][c4 * 4 + 0] = v.x; Tf[d][c4 * 4 + 1] = v.y;
        Tf[d][c4 * 4 + 2] = v.z; Tf[d][c4 * 4 + 3] = v.w;
        ushort4 cv;
        cv.x = bf16rne(v.x); cv.y = bf16rne(v.y); cv.z = bf16rne(v.z); cv.w = bf16rne(v.w);
        *(ushort4*)(Cb16 + ((size_t)b * D_ + d) * LC + c0 + c4 * 4) = cv;
    }
    __syncthreads();
    int c_l = t & 63, g = t >> 6;
    unsigned short u[32];
#pragma unroll
    for (int j = 0; j < 32; ++j) {
        int d = g * 32 + j;
        u[j] = bf16rne(Tf[d][c_l] * wm[d]);
    }
    short* dst = Ctw + ((size_t)b * LC + c0 + c_l) * D_ + g * 32;
#pragma unroll
    for (int k = 0; k < 4; ++k) *(us8*)(dst + k * 8) = *(const us8*)&u[k * 8];
}

// ---------- prep Q: Qt16[q][d] = bf16(Q[d][q]) (transposed), W[n=d][q] = bf16(Q[d][q]) ----------
__global__ void k_prep_Q(const float* __restrict__ Q, short* __restrict__ Qt16,
                         short* __restrict__ Wf) {
    int b = blockIdx.y, q0 = blockIdx.x * 64;
    __shared__ float Tf[128][65];
    int t = threadIdx.x;
    const float* Qb = Q + (size_t)b * D_ * LQ;
#pragma unroll
    for (int i = 0; i < 8; ++i) {
        int idx = t + i * 256;
        int d = idx >> 4, q4 = idx & 15;
        float4 v = *(const float4*)(Qb + (size_t)d * LQ + q0 + q4 * 4);
        Tf[d][q4 * 4 + 0] = v.x; Tf[d][q4 * 4 + 1] = v.y;
        Tf[d][q4 * 4 + 2] = v.z; Tf[d][q4 * 4 + 3] = v.w;
        ushort4 cv;
        cv.x = bf16rne(v.x); cv.y = bf16rne(v.y); cv.z = bf16rne(v.z); cv.w = bf16rne(v.w);
        *(ushort4*)(Wf + ((size_t)b * 256 + d) * LQ + q0 + q4 * 4) = cv;
    }
    __syncthreads();
    int q_l = t & 63, g = t >> 6;
    unsigned short u[32];
#pragma unroll
    for (int j = 0; j < 32; ++j) u[j] = bf16rne(Tf[g * 32 + j][q_l]);
    short* dst = Qt16 + ((size_t)b * LQ + q0 + q_l) * D_ + g * 32;
#pragma unroll
    for (int k = 0; k < 4; ++k) *(us8*)(dst + k * 8) = *(const us8*)&u[k * 8];
}

// ---------- K1: S[c][q] via MFMA, stored fp16; FUSED col-stats partials per c-tile.
// Stats computed on the f16-QUANTIZED values (bit-identical to re-reading S16). ----------
__global__ __launch_bounds__(256) void k_S_mfma(const short* __restrict__ Ctw,
                                                const short* __restrict__ Qt16,
                                                const float* __restrict__ s0,
                                                const float* __restrict__ s1,
                                                const float* __restrict__ bias,
                                                const int* __restrict__ Cmask,
                                                _Float16* __restrict__ S16,
                                                float* __restrict__ pm,
                                                float* __restrict__ pl) {
    int b = blockIdx.y;
    int cT = blockIdx.x >> 2, qT = blockIdx.x & 3;
    int c0 = cT * 128, q0 = qT * 128;
    int t = threadIdx.x, w = t >> 6, l = t & 63;
    int wm_ = w >> 1, wn = w & 1;
    __shared__ short As[128 * 64];
    __shared__ short Bs[128 * 64];
    f32x4 acc[4][4] = {};
    const short* Arow = Ctw + ((size_t)b * LC + c0) * D_;
    const short* Brow = Qt16 + ((size_t)b * LQ + q0) * D_;
    int lr = l >> 3, sl = l & 7;
    for (int kt = 0; kt < 2; ++kt) {
        __syncthreads();
#pragma unroll
        for (int i = 0; i < 4; ++i) {
            int r = w * 32 + i * 8 + lr;
            int g = sl ^ (r & 7);
            gll16(Arow + (size_t)r * D_ + kt * 64 + g * 8, &As[(w * 32 + i * 8) * 64]);
            gll16(Brow + (size_t)r * D_ + kt * 64 + g * 8, &Bs[(w * 32 + i * 8) * 64]);
        }
        __syncthreads();
#pragma unroll
        for (int ks = 0; ks < 2; ++ks) {
            int kg = ks * 4 + (l >> 4);
            bf16x8 af[4], bfr[4];
#pragma unroll
            for (int ms = 0; ms < 4; ++ms) {
                int m = wm_ * 64 + ms * 16 + (l & 15);
                af[ms] = *(const bf16x8*)&As[m * 64 + (kg ^ (m & 7)) * 8];
            }
#pragma unroll
            for (int ns = 0; ns < 4; ++ns) {
                int n = wn * 64 + ns * 16 + (l & 15);
                bfr[ns] = *(const bf16x8*)&Bs[n * 64 + (kg ^ (n & 7)) * 8];
            }
#pragma unroll
            for (int ms = 0; ms < 4; ++ms)
#pragma unroll
                for (int ns = 0; ns < 4; ++ns)
                    acc[ms][ns] = __builtin_amdgcn_mfma_f32_16x16x32_bf16(af[ms], bfr[ns], acc[ms][ns], 0, 0, 0);
        }
    }
    float bv = bias[0];
    // preload s0 + Cmask for this thread's 16 c's
    float s0v[16];
    int cmv[16];
#pragma unroll
    for (int ms = 0; ms < 4; ++ms) {
        int cb = c0 + wm_ * 64 + ms * 16 + (l >> 4) * 4;
        float4 sv = *(const float4*)(s0 + b * LC + cb);
        s0v[ms * 4 + 0] = sv.x; s0v[ms * 4 + 1] = sv.y;
        s0v[ms * 4 + 2] = sv.z; s0v[ms * 4 + 3] = sv.w;
        int4 cv = *(const int4*)(Cmask + b * LC + cb);
        cmv[ms * 4 + 0] = cv.x; cmv[ms * 4 + 1] = cv.y;
        cmv[ms * 4 + 2] = cv.z; cmv[ms * 4 + 3] = cv.w;
    }
    // stats LDS overlay on As/Bs (compute done)
    __syncthreads();
    float* Mp = (float*)As;   // [8][132] = 4224 B, fits in 16 KB
    float* Lp = (float*)Bs;
    int prow = wm_ * 4 + (l >> 4);          // 0..7
#pragma unroll
    for (int ns = 0; ns < 4; ++ns) {
        int qi = wn * 64 + ns * 16 + (l & 15);   // 0..127 within tile
        int q = q0 + qi;
        float s1v = s1[b * LQ + q] + bv;
        float vq16[16];
#pragma unroll
        for (int ms = 0; ms < 4; ++ms) {
            int cb = c0 + wm_ * 64 + ms * 16 + (l >> 4) * 4;
#pragma unroll
            for (int r = 0; r < 4; ++r) {
                float vf = acc[ms][ns][r] + s0v[ms * 4 + r] + s1v;
                _Float16 h = (_Float16)vf;
                S16[((size_t)b * LC + cb + r) * LQ + q] = h;
                vq16[ms * 4 + r] = (float)h;     // f16-quantized, matches re-read semantics
            }
        }
        float mt = NEGINF;
#pragma unroll
        for (int k = 0; k < 16; ++k) mt = fmaxf(mt, cmv[k] ? vq16[k] : NEGINF);
        float st = 0.f;
#pragma unroll
        for (int k = 0; k < 16; ++k) st += cmv[k] ? __expf(vq16[k] - mt) : 0.f;
        Mp[prow * 132 + qi] = mt;
        Lp[prow * 132 + qi] = st;
    }
    __syncthreads();
    if (t < 128) {
        float mm = Mp[t], ll = Lp[t];
#pragma unroll
        for (int g = 1; g < 8; ++g) {
            float m2 = Mp[g * 132 + t], l2 = Lp[g * 132 + t];
            float mn = fmaxf(mm, m2);
            ll = ll * __expf(mm - mn) + l2 * __expf(m2 - mn);
            mm = mn;
        }
        size_t o = ((size_t)cT * B_ + b) * LQ + q0 + t;
        pm[o] = mm; pl[o] = ll;
    }
}

// ---------- K2 (runs AFTER colstats+V2): row softmax, IN PLACE f16 -> bf16 P1 ----------
__global__ void k_rowsoftmax(_Float16* __restrict__ S16, const int* __restrict__ Qmask) {
    int row = blockIdx.x * 4 + (threadIdx.x >> 6);
    int lane = threadIdx.x & 63;
    int b = row / LC;
    _Float16* Sp = S16 + (size_t)row * LQ + lane * 8;
    f16x8 v = *(const f16x8*)Sp;
    const int* qm = Qmask + b * LQ + lane * 8;
    int4 m0 = *(const int4*)qm;
    int4 m1 = *(const int4*)(qm + 4);
    int mk[8] = {m0.x, m0.y, m0.z, m0.w, m1.x, m1.y, m1.z, m1.w};
    float vf[8];
#pragma unroll
    for (int k = 0; k < 8; ++k) vf[k] = (float)v[k];
    float mx = NEGINF;
#pragma unroll
    for (int k = 0; k < 8; ++k) if (mk[k]) mx = fmaxf(mx, vf[k]);
#pragma unroll
    for (int off = 32; off > 0; off >>= 1) mx = fmaxf(mx, __shfl_xor(mx, off, 64));
    float e[8];
    float s = 0.f;
#pragma unroll
    for (int k = 0; k < 8; ++k) { e[k] = __expf(vf[k] - mx); if (mk[k]) s += e[k]; }
#pragma unroll
    for (int off = 32; off > 0; off >>= 1) s += __shfl_xor(s, off, 64);
    float ri = 1.0f / s;
    unsigned short u[8];
#pragma unroll
    for (int k = 0; k < 8; ++k) u[k] = mk[k] ? bf16rne(e[k] * ri) : (unsigned short)0;
    *(us8*)Sp = *(const us8*)&u[0];
}

// ---------- K3b: combine CCH partials per column ----------
__global__ void k_colstats_comb(const float* __restrict__ pm, const float* __restrict__ pl,
                                float* __restrict__ colmax, float* __restrict__ colsum) {
    int idx = blockIdx.x * 256 + threadIdx.x;       // b*LQ + q
    float m = NEGINF, l = 0.f;
#pragma unroll
    for (int ch = 0; ch < CCH; ++ch) {
        float m2 = pm[(size_t)ch * B_ * LQ + idx];
        float l2 = pl[(size_t)ch * B_ * LQ + idx];
        float mn = fmaxf(m, m2);
        l = l * __expf(m - mn) + l2 * __expf(m2 - mn);
        m = mn;
    }
    colmax[idx] = m; colsum[idx] = l;
}

// ---------- K5: Wf[128+dd][q] = bf16( (1/colsum[q]) * sum_c Cb16[dd][c]*cm[c]*exp(S[c][q]-colmax[q]) ) ----------
__global__ __launch_bounds__(256) void k_V2_mfma(const short* __restrict__ Cb16,
                                                 const _Float16* __restrict__ S16,
                                                 const int* __restrict__ Cmask,
                                                 const float* __restrict__ colmax,
                                                 const float* __restrict__ colsum,
                                                 short* __restrict__ Wf) {
    int b = blockIdx.y;
    int q0 = blockIdx.x * 64;
    int t = threadIdx.x, w = t >> 6, l = t & 63;
    __shared__ short As[128 * 64];
    __shared__ short Bs[64 * 72];
    f32x4 acc[2][4] = {};
    const short* Arow = Cb16 + (size_t)b * D_ * LC;
    int lr = l >> 3, sl = l & 7;
    float cmx[16];
#pragma unroll
    for (int j2 = 0; j2 < 4; ++j2)
        *(float4*)&cmx[j2 * 4] = *(const float4*)(colmax + b * LQ + q0 + w * 16 + j2 * 4);
    const _Float16* Sq = S16 + (size_t)b * LC * LQ + q0 + w * 16;
    const int* cmb = Cmask + b * LC;

    for (int kt = 0; kt < 32; ++kt) {
        int ck = kt * 64;
        __syncthreads();
#pragma unroll
        for (int i = 0; i < 4; ++i) {
            int r = w * 32 + i * 8 + lr;
            int g = sl ^ (r & 7);
            gll16(Arow + (size_t)r * LC + ck + g * 8, &As[(w * 32 + i * 8) * 64]);
        }
        {
            float cmf = (float)cmb[ck + l];
            const _Float16* sp = Sq + (size_t)(ck + l) * LQ;
            f16x8 v0 = *(const f16x8*)sp;
            f16x8 v1 = *(const f16x8*)(sp + 8);
#pragma unroll
            for (int j = 0; j < 8; ++j)
                Bs[(w * 16 + j) * 72 + l] = (short)bf16rne(cmf * __expf((float)v0[j] - cmx[j]));
#pragma unroll
            for (int j = 0; j < 8; ++j)
                Bs[(w * 16 + 8 + j) * 72 + l] = (short)bf16rne(cmf * __expf((float)v1[j] - cmx[8 + j]));
        }
        __syncthreads();
#pragma unroll
        for (int ks = 0; ks < 2; ++ks) {
            int kg = ks * 4 + (l >> 4);
            bf16x8 af[2], bfr[4];
#pragma unroll
            for (int ms = 0; ms < 2; ++ms) {
                int m = w * 32 + ms * 16 + (l & 15);
                af[ms] = *(const bf16x8*)&As[m * 64 + (kg ^ (m & 7)) * 8];
            }
#pragma unroll
            for (int ns = 0; ns < 4; ++ns) {
                int n = ns * 16 + (l & 15);
                bfr[ns] = *(const bf16x8*)&Bs[n * 72 + kg * 8];
            }
#pragma unroll
            for (int ms = 0; ms < 2; ++ms)
#pragma unroll
                for (int ns = 0; ns < 4; ++ns)
                    acc[ms][ns] = __builtin_amdgcn_mfma_f32_16x16x32_bf16(af[ms], bfr[ns], acc[ms][ns], 0, 0, 0);
        }
    }
#pragma unroll
    for (int ms = 0; ms < 2; ++ms)
#pragma unroll
        for (int ns = 0; ns < 4; ++ns) {
            int q = q0 + ns * 16 + (l & 15);
            float csi = 1.0f / colsum[b * LQ + q];
#pragma unroll
            for (int r = 0; r < 4; ++r) {
                int dd = w * 32 + ms * 16 + (l >> 4) * 4 + r;
                Wf[((size_t)b * 256 + 128 + dd) * LQ + q] = (short)bf16rne(acc[ms][ns][r] * csi);
            }
        }
}

// ---------- K6: OUT^T GEMM, merged 256n x 128c tile, DOUBLE-BUFFERED LDS with
// counted vmcnt(6): loads for tile kt+1 stay in flight across the barrier while
// tile kt computes. Raw s_barrier (NOT __syncthreads: that would drain vmcnt(0)). ----------
__global__ __launch_bounds__(512) void k_out_mfma(const short* __restrict__ P1,
                                                  const short* __restrict__ Wf,
                                                  const float* __restrict__ C,
                                                  float* __restrict__ out) {
    int b = blockIdx.y;
    int c0 = blockIdx.x * 128;
    int t = threadIdx.x, w = t >> 6, l = t & 63;
    int wn = w & 3, wc = w >> 2;            // wave tile: n = wn*64.., c = wc*64..
    __shared__ short As[2 * 256 * 64];       // Wf rows (n), 2 x 32 KB
    __shared__ short Bs[2 * 128 * 64];       // P1 rows (c), 2 x 16 KB  -> 96 KB total
    f32x4 acc[4][4] = {};
    const short* Arow = Wf + (size_t)b * 256 * LQ;
    const short* Brow = P1 + ((size_t)b * LC + c0) * LQ;
    int lr = l >> 3, sl = l & 7;
    int g = sl ^ lr;                         // staging swizzle (row&7 == lr)

    // 6 gll16 per wave per stage
#define STAGE(p, kt)                                                              \
    {                                                                             \
        short* Ad = As + (p) * (256 * 64);                                        \
        short* Bd = Bs + (p) * (128 * 64);                                        \
        _Pragma("unroll")                                                         \
        for (int i = 0; i < 4; ++i) {                                             \
            int r = w * 32 + i * 8 + lr;                                          \
            gll16(Arow + (size_t)r * LQ + (kt) * 64 + g * 8,                      \
                  &Ad[(w * 32 + i * 8) * 64]);                                    \
        }                                                                         \
        _Pragma("unroll")                                                         \
        for (int i = 0; i < 2; ++i) {                                             \
            int r = w * 16 + i * 8 + lr;                                          \
            gll16(Brow + (size_t)r * LQ + (kt) * 64 + g * 8,                      \
                  &Bd[(w * 16 + i * 8) * 64]);                                    \
        }                                                                         \
    }

    STAGE(0, 0);
    int cur = 0;
    for (int kt = 0; kt < 8; ++kt) {
        if (kt < 7) {
            STAGE(cur ^ 1, kt + 1);
            asm volatile("s_waitcnt vmcnt(6)" ::: "memory");  // cur's 6 done, new 6 in flight
        } else {
            asm volatile("s_waitcnt vmcnt(0)" ::: "memory");
        }
        __builtin_amdgcn_s_barrier();
        __builtin_amdgcn_sched_barrier(0);
        const short* Ac = As + cur * (256 * 64);
        const short* Bc = Bs + cur * (128 * 64);
#pragma unroll
        for (int ks = 0; ks < 2; ++ks) {
            int kg = ks * 4 + (l >> 4);
            bf16x8 af[4], bfr[4];
#pragma unroll
            for (int ms = 0; ms < 4; ++ms) {
                int m = wn * 64 + ms * 16 + (l & 15);
                af[ms] = *(const bf16x8*)&Ac[m * 64 + (kg ^ (m & 7)) * 8];
            }
#pragma unroll
            for (int ns = 0; ns < 4; ++ns) {
                int cc = wc * 64 + ns * 16 + (l & 15);
                bfr[ns] = *(const bf16x8*)&Bc[cc * 64 + (kg ^ (cc & 7)) * 8];
            }
#pragma unroll
            for (int ms = 0; ms < 4; ++ms)
#pragma unroll
                for (int ns = 0; ns < 4; ++ns)
                    acc[ms][ns] = __builtin_amdgcn_mfma_f32_16x16x32_bf16(af[ms], bfr[ns], acc[ms][ns], 0, 0, 0);
        }
        __builtin_amdgcn_s_barrier();       // all waves done reading cur before overwrite
        cur ^= 1;
    }
#undef STAGE
#pragma unroll
    for (int ms = 0; ms < 4; ++ms) {
        int nb = wn * 64 + ms * 16 + (l >> 4) * 4;
#pragma unroll
        for (int ns = 0; ns < 4; ++ns) {
            int c = c0 + wc * 64 + ns * 16 + (l & 15);
#pragma unroll
            for (int r = 0; r < 4; ++r) {
                int n = nb + r;
                float a = acc[ms][ns][r];
                if (n < 128) {
                    float cv = C[((size_t)b * D_ + n) * LC + c];
                    out[((size_t)b * 512 + n) * LC + c] = cv;          // plane 0: Ct
                    out[((size_t)b * 512 + 128 + n) * LC + c] = a;     // plane 1: A
                    out[((size_t)b * 512 + 256 + n) * LC + c] = cv * a;// plane 2: Ct*A
                } else {
                    int dd = n - 128;
                    float cv = C[((size_t)b * D_ + dd) * LC + c];
                    out[((size_t)b * 512 + 384 + dd) * LC + c] = cv * a;// plane 3: Ct*Bm
                }
            }
        }
    }
}

extern "C" void kernel_launch(void* const* d_in, const int* in_sizes, int n_in,
                              void* d_out, int out_size, void* d_ws, size_t ws_size,
                              hipStream_t stream) {
    const float* C     = (const float*)d_in[0];
    const float* Q     = (const float*)d_in[1];
    const int*   Cmask = (const int*)d_in[2];
    const int*   Qmask = (const int*)d_in[3];
    const float* w_c   = (const float*)d_in[4];
    const float* w_q   = (const float*)d_in[5];
    const float* w_mul = (const float*)d_in[6];
    const float* bias  = (const float*)d_in[7];
    float* out = (float*)d_out;

    _Float16* S16 = (_Float16*)d_ws;                      // B*LC*LQ fp16  = 67.1 MB (later: P1 bf16 in place)
    short* Cb16 = (short*)(S16 + (size_t)B_ * LC * LQ);   // B*D*LC bf16   = 16.8 MB
    short* Ctw  = Cb16 + (size_t)B_ * D_ * LC;            // B*LC*D bf16   = 16.8 MB
    short* Qt16 = Ctw + (size_t)B_ * LC * D_;            // B*LQ*D bf16   =  4.2 MB
    short* Wf   = Qt16 + (size_t)B_ * LQ * D_;            // B*256*LQ bf16 =  8.4 MB
    float* s0     = (float*)(Wf + (size_t)B_ * 256 * LQ); // B*LC
    float* s1     = s0 + B_ * LC;                         // B*LQ
    float* colmax = s1 + B_ * LQ;                         // B*LQ
    float* colsum = colmax + B_ * LQ;                     // B*LQ
    float* pm     = colsum + B_ * LQ;                     // CCH*B*LQ = 1 MB
    float* pl     = pm + (size_t)CCH * B_ * LQ;           // CCH*B*LQ = 1 MB

    hipLaunchKernelGGL(k_dotw, dim3(B_ * LC / 256), dim3(256), 0, stream, C, w_c, s0, LC);
    hipLaunchKernelGGL(k_dotw, dim3(B_ * LQ / 256), dim3(256), 0, stream, Q, w_q, s1, LQ);
    hipLaunchKernelGGL(k_prep_C, dim3(LC / 64, B_), dim3(256), 0, stream, C, w_mul, Ctw, Cb16);
    hipLaunchKernelGGL(k_prep_Q, dim3(LQ / 64, B_), dim3(256), 0, stream, Q, Qt16, Wf);
    // k_S now also emits col-stats partials (pm/pl), replacing k_colstats_part
    hipLaunchKernelGGL(k_S_mfma, dim3((LC / 128) * (LQ / 128), B_), dim3(256), 0, stream,
                       Ctw, Qt16, s0, s1, bias, Cmask, S16, pm, pl);
    hipLaunchKernelGGL(k_colstats_comb, dim3(B_ * LQ / 256), dim3(256), 0, stream,
                       pm, pl, colmax, colsum);
    hipLaunchKernelGGL(k_V2_mfma, dim3(LQ / 64, B_), dim3(256), 0, stream,
                       Cb16, S16, Cmask, colmax, colsum, Wf);
    // overwrite S in place with row-softmax P1 (bf16)
    hipLaunchKernelGGL(k_rowsoftmax, dim3(B_ * LC / 4), dim3(256), 0, stream, S16, Qmask);
    hipLaunchKernelGGL(k_out_mfma, dim3(LC / 128, B_), dim3(512), 0, stream,
                       (const short*)S16, Wf, C, out);
}